// Round 7
// baseline (414.904 us; speedup 1.0000x reference)
//
#include <hip/hip_runtime.h>
#include <hip/hip_bf16.h>

// CausalDiscoveryModule: B=256, N=512, E=32, IN=512, K=10
// out[b,i,j] = gate_b * sigmoid(logit) on per-(b,i)-row top-10 of j, else 0
// logit = sum_e (c_b^2 * emb_i)[e] * emb_j[e]
//
// R12 (producer/consumer wave specialization):
//  - R11 post-mortem: unconditional inserts LOST to the while-loop (176 vs
//    162): the __any guard fires ~every iter (wave-OR of 64 lanes), so the
//    ladders ran 128x unconditionally vs ~60 data-driven passes. Convoy
//    effect: insert cost is wave-wide. While-loop restored.
//  - R8/R9/R11 model: compute ~115us (VALU-issue) + SERIALIZED 42us write
//    burst at kernel end (one residency round -> all blocks burst together;
//    hbm_pct 19-21% = burst/total across all three). R10 showed in-loop
//    fences can't overlap it.
//  - R12: 6-wave blocks (384 thr): waves 0-3 compute (R9 j-quarter while-loop
//    scan; publish raw quarter lists ONLY — merge/sigmoid/epilogue off their
//    path), waves 4-5 writers. 2 tiles per block (grid 1024 -> 4 blk/CU,
//    24 waves/CU, 16 compute-waves/CU = R8's proven regime). Writers process
//    tile t-1 while compute scans tile t (separate waves -> VALU and store
//    pipes truly overlap, m114); only the last tile's ~21us burst exposed.
//  - Double-buffered list arrays; NO LDS union/aliasing anywhere (R6 bug
//    class structurally gone). Writer compose keeps the proven fence pattern
//    (asm "" memory), far away from the scan loop (R10's mistake).
//  - Barrier discipline: both roles execute exactly 2 __syncthreads.

#define NUM_VARS 512
#define EMBED_DIM 32
#define IN_DIM 512
#define BATCH 256

typedef float nf4 __attribute__((ext_vector_type(4)));
typedef float f2 __attribute__((ext_vector_type(2)));

// ---------------- K1: context MLP -> w = c^2 [256][32], gate [256] ----------
__global__ __launch_bounds__(256) void cdm_k1(
    const float* __restrict__ ctx, const float* __restrict__ W1,
    const float* __restrict__ b1, const float* __restrict__ W2,
    const float* __restrict__ b2, const float* __restrict__ Wg,
    const float* __restrict__ bg, float* __restrict__ wws,
    float* __restrict__ gws) {
  const int bb = blockIdx.x;
  const int t = threadIdx.x;
  __shared__ float xs[512];
  __shared__ float psum[32][9];   // +1 pad
  __shared__ float hs[32];
  __shared__ float cs[32];
  const float* x = ctx + (bb << 9);
  xs[t] = x[t];
  xs[t + 256] = x[t + 256];
  __syncthreads();
  {
    const int e = t >> 3, part = t & 7;
    const float* wrow = W1 + e * 512 + part * 64;
    const float* xp = xs + part * 64;
    float a = 0.f;
#pragma unroll
    for (int m = 0; m < 64; ++m) a = fmaf(wrow[m], xp[m], a);
    psum[e][part] = a;
  }
  __syncthreads();
  if (t < 32) {
    float a = 0.f;
#pragma unroll
    for (int p = 0; p < 8; ++p) a += psum[t][p];
    hs[t] = fmaxf(a + b1[t], 0.f);
  }
  __syncthreads();
  if (t < 32) {
    const float* wrow = W2 + (t << 5);
    float a = 0.f;
#pragma unroll
    for (int k = 0; k < 32; ++k) a = fmaf(wrow[k], hs[k], a);
    float c = a + b2[t];
    cs[t] = c;
    wws[(bb << 5) + t] = c * c;
  }
  __syncthreads();
  if (t == 0) {
    float a = 0.f;
#pragma unroll
    for (int k = 0; k < 32; ++k) a = fmaf(Wg[k], cs[k], a);
    float g = a + bg[0];
    gws[bb] = 1.f / (1.f + __expf(-g));
  }
}

// strict-> shift insert: equal values keep earlier-inserted (lower j) above
#define TOP10_INSERT(av, aj, v, jn)                           \
  do {                                                        \
    _Pragma("unroll") for (int k = 9; k >= 1; --k) {          \
      bool gk = (v) > av[k];                                  \
      bool gk1 = (v) > av[k - 1];                             \
      av[k] = gk ? (gk1 ? av[k - 1] : (v)) : av[k];           \
      aj[k] = gk ? (gk1 ? aj[k - 1] : (jn)) : aj[k];          \
    }                                                         \
    bool g0 = (v) > av[0];                                    \
    av[0] = g0 ? (v) : av[0];                                 \
    aj[0] = g0 ? (jn) : aj[0];                                \
  } while (0)

// ---- K2: 6-wave block; waves 0-3 scan (j-quarters), waves 4-5 write --------
__global__ __launch_bounds__(384, 6) void cdm_k2(
    const float* __restrict__ emb, const float* __restrict__ wws,
    const float* __restrict__ gws, float* __restrict__ out) {
  const int lane = threadIdx.x & 63;
  const int wv = threadIdx.x >> 6;   // 0-3 compute, 4-5 writer
  const int G = __builtin_amdgcn_readfirstlane(blockIdx.x);

  // double-buffered quarter lists (no unions, no aliasing):
  __shared__ float mvv[2][4][10][64];            // 20480 B, lane-minor
  __shared__ unsigned short mjj[2][4][10][64];   // 10240 B
  __shared__ __align__(16) float rowbuf[2][2][512];  // 8192 B, per-writer

  if (wv < 4) {
    // =================== compute wave: j-quarter scans =====================
    const int q = wv;
    const int jbase = __builtin_amdgcn_readfirstlane(q << 7);
    const f2* eb = reinterpret_cast<const f2*>(emb);
    for (int t = 0; t < 2; ++t) {
      const int tile = (G << 1) | t;
      const int r0 = tile << 6;
      const int b = r0 >> 9;
      const int i = (r0 + lane) & 511;

      f2 sv2[16];
      {
        const f2* wb = reinterpret_cast<const f2*>(wws + (b << 5));
        const f2* ei = reinterpret_cast<const f2*>(emb + (i << 5));
#pragma unroll
        for (int p = 0; p < 16; ++p) sv2[p] = wb[p] * ei[p];
      }

      float hv[10];
      int hj[10];
#pragma unroll
      for (int k = 0; k < 10; ++k) { hv[k] = -1e30f; hj[k] = 0; }

      for (int it = 0; it < 32; ++it) {
        const int j0 = jbase + (it << 2);
        const f2* e0 = eb + ((j0 + 0) << 4);
        const f2* e1 = eb + ((j0 + 1) << 4);
        const f2* e2 = eb + ((j0 + 2) << 4);
        const f2* e3 = eb + ((j0 + 3) << 4);
        f2 c0 = {0.f, 0.f}, c1 = {0.f, 0.f}, c2 = {0.f, 0.f}, c3 = {0.f, 0.f};
#pragma unroll
        for (int p = 0; p < 16; ++p) {
          c0 += sv2[p] * e0[p];   // v_pk_fma_f32
          c1 += sv2[p] * e1[p];
          c2 += sv2[p] * e2[p];
          c3 += sv2[p] * e3[p];
        }
        float a0 = c0.x + c0.y, a1 = c1.x + c1.y;
        float a2 = c2.x + c2.y, a3 = c3.x + c3.y;

        const float thr = hv[9];
        int p0 = a0 > thr, p1 = a1 > thr, p2 = a2 > thr, p3 = a3 > thr;
        while (__any(p0 | p1 | p2 | p3)) {
          if (p0 | p1 | p2 | p3) {
            float v;
            int jn;
            if (p0) { v = a0; jn = j0; p0 = 0; }
            else if (p1) { v = a1; jn = j0 + 1; p1 = 0; }
            else if (p2) { v = a2; jn = j0 + 2; p2 = 0; }
            else { v = a3; jn = j0 + 3; p3 = 0; }
            TOP10_INSERT(hv, hj, v, jn);
          }
          const float nt = hv[9];
          p0 = p0 && (a0 > nt);
          p1 = p1 && (a1 > nt);
          p2 = p2 && (a2 > nt);
          p3 = p3 && (a3 > nt);
        }
      }

      // publish raw quarter list for this tile (merge happens on writers)
#pragma unroll
      for (int k = 0; k < 10; ++k) {
        mvv[t][q][k][lane] = hv[k];
        mjj[t][q][k][lane] = (unsigned short)hj[k];
      }
      __syncthreads();   // barrier #1 / #2
    }
    // compute waves exit; writers keep running.
  } else {
    // ============================ writer wave ==============================
    const int W = wv - 4;            // writes rows [32W, 32W+32) of each tile
    float* rb = &rowbuf[W][0][0];    // [2][512] private compose buffer
    nf4* rb4 = reinterpret_cast<nf4*>(rb);
    const nf4 z4 = {0.f, 0.f, 0.f, 0.f};
#pragma unroll
    for (int s = 0; s < 4; ++s) rb4[(s << 6) + lane] = z4;  // pre-zero once
    asm volatile("" ::: "memory");

    __syncthreads();   // barrier #1: tile-0 lists published

    for (int tt = 0; tt < 2; ++tt) {
      // ---- merge 4 quarter-lists (ascending-j order => exact jax ties) ----
      const int tile = (G << 1) | tt;
      const int r0 = tile << 6;
      float fv[10];
      int fj[10];
#pragma unroll
      for (int k = 0; k < 10; ++k) {
        fv[k] = mvv[tt][0][k][lane];
        fj[k] = (int)mjj[tt][0][k][lane];
      }
#pragma unroll
      for (int m = 1; m < 4; ++m) {
#pragma unroll
        for (int k = 0; k < 10; ++k) {
          float v = mvv[tt][m][k][lane];
          int jn = (int)mjj[tt][m][k][lane];
          if (v > fv[9]) TOP10_INSERT(fv, fj, v, jn);
        }
      }
      const float gateb = gws[r0 >> 9];
      float oval[10];
#pragma unroll
      for (int k = 0; k < 10; ++k) oval[k] = gateb / (1.f + __expf(-fv[k]));

      // ---- compose + dense one-pass write: 16 phases of 2 rows ------------
      // scatter -> fence -> read b128 + store dwordx4 -> fence -> rezero.
      // Fences are compile-time only (stop alias reordering of float*-scatter
      // vs nf4*-read, the R6 bug); HW in-wave DS order gives visibility.
      for (int p = 0; p < 16; ++p) {
        const int rbase = (W << 5) | (p << 1);   // even row offset in tile
        const bool own = (lane >> 1) == (rbase >> 1);  // lanes rbase, rbase+1
        const int slot = lane & 1;
        if (own) {
          float* dst = rb + (slot << 9);
#pragma unroll
          for (int k = 0; k < 10; ++k) dst[fj[k]] = oval[k];
        }
        asm volatile("" ::: "memory");   // scatter before reads
#pragma unroll
        for (int s = 0; s < 2; ++s) {
          nf4 lo = rb4[(s << 7) + lane];        // floats [0,256) of row s
          nf4 hi = rb4[(s << 7) + 64 + lane];   // floats [256,512)
          nf4* ob =
              reinterpret_cast<nf4*>(out + ((size_t)(r0 + rbase + s) << 9));
          ob[lane] = lo;                        // coalesced dwordx4
          ob[lane + 64] = hi;
        }
        asm volatile("" ::: "memory");   // reads before rezero
        if (own) {
          float* dst = rb + (slot << 9);
#pragma unroll
          for (int k = 0; k < 10; ++k) dst[fj[k]] = 0.f;
        }
        asm volatile("" ::: "memory");   // rezero before next scatter
      }

      if (tt == 0) __syncthreads();   // barrier #2: tile-1 lists published
      // (tile 0 was processed concurrently with compute's tile-1 scan)
    }
  }
}

extern "C" void kernel_launch(void* const* d_in, const int* in_sizes, int n_in,
                              void* d_out, int out_size, void* d_ws,
                              size_t ws_size, hipStream_t stream) {
  const float* ctx = (const float*)d_in[0];
  const float* emb = (const float*)d_in[1];
  const float* W1 = (const float*)d_in[2];
  const float* b1 = (const float*)d_in[3];
  const float* W2 = (const float*)d_in[4];
  const float* b2 = (const float*)d_in[5];
  const float* Wg = (const float*)d_in[6];
  const float* bg = (const float*)d_in[7];
  float* out = (float*)d_out;
  float* wws = (float*)d_ws;            // 256*32 floats: c^2
  float* gws = wws + BATCH * EMBED_DIM; // 256 floats: gate

  cdm_k1<<<BATCH, 256, 0, stream>>>(ctx, W1, b1, W2, b2, Wg, bg, wws, gws);
  cdm_k2<<<1024, 384, 0, stream>>>(emb, wws, gws, out);
}